// Round 10
// baseline (298.274 us; speedup 1.0000x reference)
//
#include <hip/hip_runtime.h>

#define B_   8
#define C_   256
#define TC_  512
#define HW_  2304   // 48*48
#define EPS_ 1e-6f
#define JS_  8      // column splits (288 cols each)

typedef __bf16 bf16_t;
typedef __bf16 bf16x8 __attribute__((ext_vector_type(8)));
typedef __bf16 bf16x4_t __attribute__((ext_vector_type(4)));
typedef float  f32x4 __attribute__((ext_vector_type(4)));
typedef unsigned int  u32;
typedef unsigned int  u32x4 __attribute__((ext_vector_type(4)));
typedef long long     i64;
typedef unsigned char u8;

__device__ __forceinline__ u8 to_fp8(float v) {
    return (u8)(__builtin_amdgcn_cvt_pk_fp8_f32(v, v, 0, false) & 0xff);
}

// ---------------------------------------------------------------------------
// W -> fragment-major bf16 (unchanged from round 8).
// ---------------------------------------------------------------------------
__global__ __launch_bounds__(256)
void wfrag_kernel(const float* __restrict__ wq, const float* __restrict__ wk,
                  const float* __restrict__ wv,
                  bf16_t* __restrict__ oq, bf16_t* __restrict__ ok,
                  bf16_t* __restrict__ ov)
{
    const int fid = blockIdx.x * 4 + (threadIdx.x >> 6);   // 0..639
    const int lane = threadIdx.x & 63;
    const int l16 = lane & 15, quad = lane >> 4;

    const float* src; bf16_t* dst; int cin, f;
    if (fid < 128)      { src = wq; dst = oq; cin = C_;  f = fid; }
    else if (fid < 384) { src = wk; dst = ok; cin = TC_; f = fid - 128; }
    else                { src = wv; dst = ov; cin = TC_; f = fid - 384; }
    const int nks = cin / 32;
    const int ot = f / nks, ks = f % nks;

    const float* s = src + (size_t)(ot * 16 + l16) * cin + ks * 32 + quad * 8;
    float4 a = *(const float4*)(s);
    float4 b = *(const float4*)(s + 4);
    bf16x8 o;
    o[0] = (__bf16)a.x; o[1] = (__bf16)a.y; o[2] = (__bf16)a.z; o[3] = (__bf16)a.w;
    o[4] = (__bf16)b.x; o[5] = (__bf16)b.y; o[6] = (__bf16)b.z; o[7] = (__bf16)b.w;
    *(bf16x8*)(dst + (size_t)f * 512 + lane * 8) = o;
}

// ---------------------------------------------------------------------------
// Fused 1x1-conv stage.  Compute unchanged from round 8; the q/k/v STORES
// now target the attention's fragment-major fp8 layouts:
//  q (FRAG_A=false): row-major [b][n][C]  (A-operand, per-wave private reads)
//  k (FRAG_A=true):  K-frag pairs: addr = ((b*144 + n>>4)*4 + pair)*1024
//                    + (quadk*16 + j16)*16 + slot*8 + byte
//                    frag t: pair=t>>1=wv, slot=t&1=p>>1; lane=(quadk,j16)
//  v (DO_V):         V-frag pairs: addr = ((b*72 + jt)*8 + ct>>1)*1024
//                    + (quadv*16 + c16)*16 + (ct&1)*8 + byte
// One fragment-pair = 1 KB read as a single coalesced b128 wave-load in attn.
// ---------------------------------------------------------------------------
template<int CIN, bool DO_V, bool FRAG_A>
__global__ __launch_bounds__(256, 4)
void convqkv_kernel(const float* __restrict__ X, const bf16_t* __restrict__ Wa,
                    const bf16_t* __restrict__ Wvp, u8* __restrict__ outA,
                    u8* __restrict__ outV)
{
    const int bid = blockIdx.x;
    const int b  = bid & 7;
    const int n0 = (bid >> 3) * 16;
    const int tid = threadIdx.x;
    const int wv = tid >> 6;
    const int lane = tid & 63;
    const int quad = lane >> 4, l16 = lane & 15;
    const int NKS = CIN / 32;

    __shared__ bf16_t T[16][CIN + 8];
    __shared__ float ssp[4][16];

    {
        const float* Xb = X + (size_t)b * CIN * HW_ + n0;
        const int cl = tid >> 2;
        const int n4 = (tid & 3) * 4;
#pragma unroll
        for (int cp = 0; cp < CIN; cp += 64) {
            float4 v = *(const float4*)(Xb + (size_t)(cp + cl) * HW_ + n4);
            T[n4 + 0][cp + cl] = (__bf16)v.x;
            T[n4 + 1][cp + cl] = (__bf16)v.y;
            T[n4 + 2][cp + cl] = (__bf16)v.z;
            T[n4 + 3][cp + cl] = (__bf16)v.w;
        }
    }
    __syncthreads();

    bf16x8 af[CIN / 32];
#pragma unroll
    for (int ks = 0; ks < CIN / 32; ks++)
        af[ks] = *(const bf16x8*)(&T[l16][ks * 32 + quad * 8]);

    const int ot0 = wv * 4;

    f32x4 accK[4];
#pragma unroll
    for (int p = 0; p < 4; p++) accK[p] = (f32x4){0.f, 0.f, 0.f, 0.f};
    {
        const bf16_t* wbase = Wa + ((size_t)ot0 * NKS) * 512 + lane * 8;
#pragma unroll
        for (int ks = 0; ks < CIN / 32; ks++)
#pragma unroll
            for (int p = 0; p < 4; p++) {
                bf16x8 bw = *(const bf16x8*)(wbase + (size_t)(p * NKS + ks) * 512);
                accK[p] = __builtin_amdgcn_mfma_f32_16x16x32_bf16(af[ks], bw, accK[p], 0, 0, 0);
            }
    }

    {
        float ssr[4];
#pragma unroll
        for (int r = 0; r < 4; r++) {
            float ss = accK[0][r] * accK[0][r] + accK[1][r] * accK[1][r]
                     + accK[2][r] * accK[2][r] + accK[3][r] * accK[3][r];
            ss += __shfl_xor(ss, 1);
            ss += __shfl_xor(ss, 2);
            ss += __shfl_xor(ss, 4);
            ss += __shfl_xor(ss, 8);
            ssr[r] = ss;
        }
        if (l16 == 0) {
#pragma unroll
            for (int r = 0; r < 4; r++) ssp[wv][quad * 4 + r] = ssr[r];
        }
    }

    f32x4 accV[4];
    if (DO_V) {
#pragma unroll
        for (int p = 0; p < 4; p++) accV[p] = (f32x4){0.f, 0.f, 0.f, 0.f};
        const bf16_t* wbase = Wvp + ((size_t)ot0 * NKS) * 512 + lane * 8;
#pragma unroll
        for (int ks = 0; ks < CIN / 32; ks++)
#pragma unroll
            for (int p = 0; p < 4; p++) {
                bf16x8 aw = *(const bf16x8*)(wbase + (size_t)(p * NKS + ks) * 512);
                accV[p] = __builtin_amdgcn_mfma_f32_16x16x32_bf16(aw, af[ks], accV[p], 0, 0, 0);
            }
    }

    __syncthreads();

    float scale[4];
#pragma unroll
    for (int r = 0; r < 4; r++) {
        int px = quad * 4 + r;
        float s = ssp[0][px] + ssp[1][px] + ssp[2][px] + ssp[3][px];
        scale[r] = 1.0f / fmaxf(sqrtf(s), EPS_);
    }

    if (FRAG_A) {
        // K frag-major: value (n = n0+quad*4+r, o = wv*64+p*16+l16)
        u8* kfb = outA + (((size_t)b * 144 + (n0 >> 4)) * 4 + wv) * 1024;
#pragma unroll
        for (int p = 0; p < 4; p++)
#pragma unroll
            for (int r = 0; r < 4; r++) {
                int lane_k = ((2 * p + (l16 >> 3)) & 3) * 16 + quad * 4 + r;
                kfb[lane_k * 16 + (p >> 1) * 8 + (l16 & 7)] = to_fp8(accK[p][r] * scale[r]);
            }
    } else {
        u8* oa = outA + ((size_t)b * HW_ + n0 + quad * 4) * C_ + l16;
#pragma unroll
        for (int p = 0; p < 4; p++)
#pragma unroll
            for (int r = 0; r < 4; r++)
                oa[(size_t)r * C_ + (ot0 + p) * 16] = to_fp8(accK[p][r] * scale[r]);
    }

    if (DO_V) {
        // V frag-major: value (c = wv*64+p*16+quad*4+r, j = n0+l16)
        u8* vfb = outV + (((size_t)b * 72 + (n0 >> 5)) * 8 + wv * 2) * 1024;
        const int quad_v = 2 * ((n0 >> 4) & 1) + (l16 >> 3);
#pragma unroll
        for (int p = 0; p < 4; p++)
#pragma unroll
            for (int r = 0; r < 4; r++) {
                int lane_v = quad_v * 16 + quad * 4 + r;
                vfb[(p >> 1) * 1024 + lane_v * 16 + (p & 1) * 8 + (l16 & 7)]
                    = to_fp8(accV[p][r]);
            }
    }
}

// ---------------------------------------------------------------------------
// Attention partials — barrier-free, wave-autonomous.
// Each wave owns ONE 16-row m-tile; K/V stream global->VGPR as coalesced
// 1-KB b128 fragment-pair loads (frag-major layouts); P round-trip through
// wave-private LDS (lgkmcnt only).  No __syncthreads anywhere.
// Grid: bid -> b = bid&7 (XCD), rr = bid>>3: js = rr&7, blk = rr>>3 (0..35),
// wave wv -> m-tile blk*4+wv.
// ---------------------------------------------------------------------------
__global__ __launch_bounds__(256, 3)
void attn_part_kernel(const u8* __restrict__ q8, const u8* __restrict__ kf,
                      const u8* __restrict__ vf,
                      bf16_t* __restrict__ Opart, float* __restrict__ lpart)
{
    const int bid = blockIdx.x;
    const int b   = bid & 7;
    const int rr  = bid >> 3;
    const int js  = rr & 7;
    const int blk = rr >> 3;             // 0..35
    const int wv   = threadIdx.x >> 6;
    const int lane = threadIdx.x & 63;
    const int quad = lane >> 4;
    const int l16  = lane & 15;
    const int row0 = (blk * 4 + wv) * 16;

    __shared__ u8 Psh[4 * 768];
    u8* pw = Psh + wv * 768;

    // Q fragments (A-operand), row-major q8
    i64 aq[8];
    {
        const u8* qr = q8 + (size_t)b * HW_ * C_ + (size_t)(row0 + l16) * C_ + quad * 8;
#pragma unroll
        for (int t = 0; t < 8; t++) aq[t] = *(const i64*)(qr + t * 32);
    }

    f32x4 O[16];
#pragma unroll
    for (int i = 0; i < 16; i++) O[i] = (f32x4){0.f, 0.f, 0.f, 0.f};
    float lsum[4] = {0.f, 0.f, 0.f, 0.f};

    const u8* kbase = kf + ((size_t)(b * 144 + js * 18) * 4) * 1024 + lane * 16;
    const u8* vbase = vf + ((size_t)(b * 72  + js * 9 ) * 8) * 1024 + lane * 16;
    const u32 sel = (quad < 2) ? 0x06040200u : 0x07050301u;

    for (int tt = 0; tt < 9; tt++) {
        const u8* kb = kbase + (size_t)tt * 8192;   // subtile s0: pairs 0..3, s1: 4..7
        const u8* vb = vbase + (size_t)tt * 8192;   // ct-pairs 0..7

        // ---- QK^T: 8 coalesced b128 loads -> 16 K frags -> 16 MFMA ----
        u32x4 kd[8];
#pragma unroll
        for (int i = 0; i < 8; i++) kd[i] = *(const u32x4*)(kb + i * 1024);
        f32x4 s0 = (f32x4){0.f,0.f,0.f,0.f}, s1 = (f32x4){0.f,0.f,0.f,0.f};
#pragma unroll
        for (int p = 0; p < 4; p++) {
            i64 b00 = (i64)kd[p][0]     | ((i64)kd[p][1]     << 32);
            i64 b01 = (i64)kd[p][2]     | ((i64)kd[p][3]     << 32);
            i64 b10 = (i64)kd[4 + p][0] | ((i64)kd[4 + p][1] << 32);
            i64 b11 = (i64)kd[4 + p][2] | ((i64)kd[4 + p][3] << 32);
            s0 = __builtin_amdgcn_mfma_f32_16x16x32_fp8_fp8(aq[2 * p],     b00, s0, 0, 0, 0);
            s0 = __builtin_amdgcn_mfma_f32_16x16x32_fp8_fp8(aq[2 * p + 1], b01, s0, 0, 0, 0);
            s1 = __builtin_amdgcn_mfma_f32_16x16x32_fp8_fp8(aq[2 * p],     b10, s1, 0, 0, 0);
            s1 = __builtin_amdgcn_mfma_f32_16x16x32_fp8_fp8(aq[2 * p + 1], b11, s1, 0, 0, 0);
        }

        // ---- exp, lsum, P (fp8 col-interleaved) -> wave-private LDS ----
#pragma unroll
        for (int r = 0; r < 4; r++) {
            float p0 = __expf(s0[r] * 0.0625f), p1 = __expf(s1[r] * 0.0625f);
            lsum[r] += p0 + p1;
            u32 w = __builtin_amdgcn_cvt_pk_fp8_f32(p0, p1, 0, false);
            *(short*)(pw + (quad * 4 + r) * 48 + l16 * 2) = (short)w;
        }
        i64 ap;
        {
            u32x4 d = *(const u32x4*)(pw + l16 * 48 + (quad & 1) * 16);
            u32 lo = __builtin_amdgcn_perm(d[1], d[0], sel);
            u32 hi = __builtin_amdgcn_perm(d[3], d[2], sel);
            ap = ((i64)hi << 32) | (i64)lo;
        }

        // ---- P.V: 8 coalesced b128 loads -> 16 V frags -> 16 MFMA ----
        u32x4 vd[8];
#pragma unroll
        for (int u = 0; u < 8; u++) vd[u] = *(const u32x4*)(vb + u * 1024);
#pragma unroll
        for (int u = 0; u < 8; u++) {
            i64 bv0 = (i64)vd[u][0] | ((i64)vd[u][1] << 32);
            i64 bv1 = (i64)vd[u][2] | ((i64)vd[u][3] << 32);
            O[2 * u]     = __builtin_amdgcn_mfma_f32_16x16x32_fp8_fp8(ap, bv0, O[2 * u],     0, 0, 0);
            O[2 * u + 1] = __builtin_amdgcn_mfma_f32_16x16x32_fp8_fp8(ap, bv1, O[2 * u + 1], 0, 0, 0);
        }
    }

    // ---- lsum reduction across the 16-lane col groups ----
#pragma unroll
    for (int r = 0; r < 4; r++) {
        float t0 = lsum[r];
        t0 += __shfl_xor(t0, 1); t0 += __shfl_xor(t0, 2);
        t0 += __shfl_xor(t0, 4); t0 += __shfl_xor(t0, 8);
        lsum[r] = t0;
    }
    float* lp = lpart + (size_t)(js * B_ + b) * HW_;
    if (l16 == 0) {
        float4 a0; a0.x = lsum[0]; a0.y = lsum[1]; a0.z = lsum[2]; a0.w = lsum[3];
        *(float4*)(lp + row0 + quad * 4) = a0;
    }

    bf16_t* op = Opart + (size_t)(js * B_ + b) * C_ * HW_;
#pragma unroll
    for (int ct = 0; ct < 16; ct++) {
        int c = ct * 16 + l16;
        bf16x4_t v0;
        v0[0] = (__bf16)O[ct][0]; v0[1] = (__bf16)O[ct][1];
        v0[2] = (__bf16)O[ct][2]; v0[3] = (__bf16)O[ct][3];
        *(bf16x4_t*)(op + (size_t)c * HW_ + row0 + quad * 4) = v0;
    }
}

// ---------------------------------------------------------------------------
// out[b][c][n] = x + alpha * (sum_js Opart) / (sum_js lpart[b][n])
// ---------------------------------------------------------------------------
__global__ __launch_bounds__(256)
void epilogue_kernel(const float* __restrict__ x, const bf16_t* __restrict__ Opart,
                     const float* __restrict__ lpart, const float* __restrict__ alphaPtr,
                     float* __restrict__ out, int JS)
{
    const float a = *alphaPtr;
    const size_t S = (size_t)B_ * C_ * HW_;
    size_t flat = ((size_t)blockIdx.x * 256 + threadIdx.x) * 4;
    int bc = (int)(flat / HW_);
    int n  = (int)(flat % HW_);
    int b  = bc >> 8;
    float4 xv = *(const float4*)(x + flat);
    float s0 = 0.f, s1 = 0.f, s2 = 0.f, s3 = 0.f;
    float l0 = 0.f, l1 = 0.f, l2 = 0.f, l3 = 0.f;
    for (int js = 0; js < JS; js++) {
        bf16x4_t ov = *(const bf16x4_t*)(Opart + (size_t)js * S + flat);
        s0 += (float)ov[0]; s1 += (float)ov[1];
        s2 += (float)ov[2]; s3 += (float)ov[3];
        float4 lv = *(const float4*)(lpart + (size_t)(js * B_ + b) * HW_ + n);
        l0 += lv.x; l1 += lv.y; l2 += lv.z; l3 += lv.w;
    }
    float4 r;
    r.x = xv.x + a * s0 / l0;
    r.y = xv.y + a * s1 / l1;
    r.z = xv.z + a * s2 / l2;
    r.w = xv.w + a * s3 / l3;
    *(float4*)(out + flat) = r;
}

// ---------------------------------------------------------------------------
extern "C" void kernel_launch(void* const* d_in, const int* in_sizes, int n_in,
                              void* d_out, int out_size, void* d_ws, size_t ws_size,
                              hipStream_t stream)
{
    (void)in_sizes; (void)n_in; (void)out_size; (void)ws_size;
    const float* x     = (const float*)d_in[0];
    const float* token = (const float*)d_in[1];
    const float* Wq    = (const float*)d_in[2];
    const float* Wk    = (const float*)d_in[3];
    const float* Wv    = (const float*)d_in[4];
    const float* alpha = (const float*)d_in[5];
    float* out = (float*)d_out;

    const size_t S = (size_t)B_ * HW_ * C_;   // 4,718,592 elements

    char* ws = (char*)d_ws;
    bf16_t* WqL   = (bf16_t*)(ws + 6 * S);       // frag-major, 128 KB
    bf16_t* WkL   = WqL + (size_t)C_ * C_;       // frag-major, 256 KB
    bf16_t* WvL   = WkL + (size_t)C_ * TC_;      // frag-major, 256 KB
    u8*     q8    = (u8*)(ws + 7 * S);           // fp8 row-major [b][n][C]
    u8*     kf    = (u8*)(ws + 8 * S);           // fp8 K frag-major (S bytes)
    u8*     vf    = (u8*)(ws + 9 * S);           // fp8 V frag-major (S bytes)
    bf16_t* Opart = (bf16_t*)(ws + 12 * S);      // [js][b][c][n] bf16
    float*  lpart = (float*)(ws + (12 + 2 * (size_t)JS_) * S);

    wfrag_kernel<<<dim3(160), dim3(256), 0, stream>>>(Wq, Wk, Wv, WqL, WkL, WvL);
    convqkv_kernel<C_,  false, false><<<dim3(B_ * HW_ / 16), dim3(256), 0, stream>>>(x,     WqL, nullptr, q8, nullptr);
    convqkv_kernel<TC_, true,  true ><<<dim3(B_ * HW_ / 16), dim3(256), 0, stream>>>(token, WkL, WvL,     kf, vf);
    attn_part_kernel<<<dim3(JS_ * B_ * (HW_ / 64)), dim3(256), 0, stream>>>(q8, kf, vf, Opart, lpart);
    epilogue_kernel<<<dim3((int)(S / 1024)), dim3(256), 0, stream>>>(x, Opart, lpart, alpha, out, JS_);
}